// Round 18
// baseline (905.273 us; speedup 1.0000x reference)
//
#include <hip/hip_runtime.h>
#include <math.h>
#include <stddef.h>
#include <stdint.h>

// ---------------------------------------------------------------------------
// ReNet: patches -> vert bidir LSTM -> horiz bidir LSTM -> dense+relu
// B=64, I=J=32, D=12, HID=256, FC=1024.
// Round 18: sweep R-pipeline moved from a register kc-ring to LDS DMA:
// 64KB per-kc slices staged via global_load_lds, double-buffered (144KB LDS),
// dual-q MFMA per wave off one shared h-fragment. Registers freed (no bfr
// ring) -> spill structurally impossible. Gemms/prep/zxv identical to r17.
// ---------------------------------------------------------------------------

namespace {

typedef __bf16 bf16x8 __attribute__((ext_vector_type(8)));
typedef float f32x4 __attribute__((ext_vector_type(4)));
typedef __attribute__((address_space(1))) unsigned int as1_uint;
typedef __attribute__((address_space(3))) unsigned int as3_uint;

__device__ __forceinline__ float bf2f(ushort u) {
  return __builtin_bit_cast(float, (unsigned int)u << 16);
}
__device__ __forceinline__ ushort f2bf(float f) {
  unsigned int u = __builtin_bit_cast(unsigned int, f);
  u += 0x7fffu + ((u >> 16) & 1u);
  return (ushort)(u >> 16);
}
__device__ __forceinline__ unsigned int packbf(float a, float b) {
  return (unsigned int)f2bf(a) | ((unsigned int)f2bf(b) << 16);
}
__device__ __forceinline__ float sigm(float x) {
  return __fdividef(1.f, 1.f + __expf(-x));
}
__device__ __forceinline__ float tanh_(float x) {
  return 2.f * sigm(2.f * x) - 1.f;
}
__device__ __forceinline__ f32x4 mfma16(bf16x8 a, bf16x8 b, f32x4 c) {
  return __builtin_amdgcn_mfma_f32_16x16x32_bf16(a, b, c, 0, 0, 0);
}
__device__ __forceinline__ void load_lds16(const void* g, void* l) {
  __builtin_amdgcn_global_load_lds((const as1_uint*)g, (as3_uint*)l, 16, 0, 0);
}

// Zf fragment-major layout, per (dir, rb16) [rb16 = 16-row group, 0..127]:
// 65536 uint4. index = ((seq*2 + q)*2 + p)*512 + tidz ; components = gates.
// uint packs bf16 local rows (2*n2l, 2*n2l+1), n2l = kg*2+p (0..7),
// tidz = w*64 + kg*16 + l16, hcol = w*32 + q*16 + l16.
// dir stride = 128*65536 uint4.

// --------------------------------------------------------------------------
// merged transpose: f32 [512][1024] -> bf16 [1024][512], 3 srcs by blockIdx.y
__global__ __launch_bounds__(256) void transpose_all(
    const float* __restrict__ s0, const float* __restrict__ s1,
    const float* __restrict__ s2, ushort* __restrict__ d0,
    ushort* __restrict__ d1, ushort* __restrict__ d2) {
  const int which = blockIdx.y;
  const float* in = (which == 0) ? s0 : (which == 1) ? s1 : s2;
  ushort* out = (which == 0) ? d0 : (which == 1) ? d1 : d2;
  const int idx = blockIdx.x * 256 + threadIdx.x;  // 524288 ids
  const int n = idx >> 9, k = idx & 511;
  out[idx] = f2bf(in[k * 1024 + n]);
}

// --------------------------------------------------------------------------
// merged rfrag: repack r [256][1024] f32 -> MFMA B-fragment-major bf16,
// 4 srcs by blockIdx.y.
__global__ __launch_bounds__(256) void rfrag_all(
    const float* __restrict__ r0, const float* __restrict__ r1,
    const float* __restrict__ r2, const float* __restrict__ r3,
    ushort* __restrict__ out) {
  const int which = blockIdx.y;
  const float* r = (which == 0) ? r0 : (which == 1) ? r1 : (which == 2) ? r2 : r3;
  ushort* o = out + (size_t)which * 262144;
  const int id = blockIdx.x * 256 + threadIdx.x;  // 32768 ids
  const int lane = id & 63, kc = (id >> 6) & 7, tile = id >> 9;
  const int kbase = (kc << 5) + ((lane >> 4) << 3);
  const int col = (tile << 4) + (lane & 15);
  ushort tmp[8];
#pragma unroll
  for (int j = 0; j < 8; ++j) tmp[j] = f2bf(r[(size_t)(kbase + j) * 1024 + col]);
  *(uint4*)&o[(size_t)id << 3] = *(const uint4*)tmp;
}

// --------------------------------------------------------------------------
// Vertical input projection -> fragment-major Zf. Block (jp, b, dir), 256 thr.
__global__ __launch_bounds__(256) void zxv3_kernel(
    const float* __restrict__ x, const float* __restrict__ k0_,
    const float* __restrict__ b0_, const float* __restrict__ k1_,
    const float* __restrict__ b1_, uint4* __restrict__ Zf) {
  const int tid = threadIdx.x;
  const int jp = blockIdx.x, b = blockIdx.y, dir = blockIdx.z;
  const int j0 = jp << 1;
  const float* kw_ = dir ? k1_ : k0_;
  const float* bw_ = dir ? b1_ : b0_;
  __shared__ float ps[2][32][12];
  for (int e = tid; e < 2 * 32 * 12; e += 256) {
    const int jj = e / 384, rest = e - jj * 384;
    const int i = rest / 12, qq = rest - i * 12;
    const int pr = qq / 6, rem = qq - pr * 6;
    ps[jj][i][qq] =
        x[((size_t)((b * 64 + i * 2 + pr) * 64) + (j0 + jj) * 2 + rem / 3) * 3 + rem % 3];
  }
  __syncthreads();
  float kr[12][4], br[4];
#pragma unroll
  for (int qq = 0; qq < 12; ++qq)
#pragma unroll
    for (int g = 0; g < 4; ++g) kr[qq][g] = kw_[qq * 1024 + (g << 8) + tid];
#pragma unroll
  for (int g = 0; g < 4; ++g) br[g] = bw_[(g << 8) + tid];

  const int wv = tid >> 5, qv = (tid >> 4) & 1, l16v = tid & 15;
  const int rb16 = (b << 1) + (jp >> 3);
  const int n2l = jp & 7;
  const int kgz = n2l >> 1, pz = n2l & 1;
  const int tidz = (wv << 6) + (kgz << 4) + l16v;
  uint4* base = Zf + ((size_t)dir * 128 + rb16) * 65536;

  for (int i = 0; i < 32; ++i) {
    float z0[4], z1[4];
#pragma unroll
    for (int g = 0; g < 4; ++g) { z0[g] = br[g]; z1[g] = br[g]; }
#pragma unroll
    for (int qq = 0; qq < 12; ++qq) {
      const float p0 = ps[0][i][qq], p1 = ps[1][i][qq];
#pragma unroll
      for (int g = 0; g < 4; ++g) {
        z0[g] += p0 * kr[qq][g];
        z1[g] += p1 * kr[qq][g];
      }
    }
    uint4 o;
    o.x = packbf(z0[0], z1[0]);
    o.y = packbf(z0[1], z1[1]);
    o.z = packbf(z0[2], z1[2]);
    o.w = packbf(z0[3], z1[3]);
    base[(size_t)((((i << 1) + qv) << 1) + pz) * 512 + tidz] = o;
  }
}

// --------------------------------------------------------------------------
// LSTM sweep, round 18: LDS-DMA R pipeline.
// Grid (128 rowblk, 2 dir) = 256 blocks (1/CU), 512 thr (8 waves).
// Block owns rows [rb*16,+16) x all 256 h. Wave w owns h-cols [w*32,+32),
// BOTH q passes per kc (one shared h-fragment feeds 8 MFMAs).
// R streamed as per-kc 64KB slices via global_load_lds, double-buffered:
// slice kc+1 issued at START of iter kc, drained at its end-barrier.
// Slice 0 for step t+1 re-staged at kc7. zx for t+1 loaded after all stage
// issues. h in 2x8KB LDS; epilogue barrier closes the step.
__global__ __launch_bounds__(512) void lstm_sweep12(
    const uint4* __restrict__ Zf, const uint4* __restrict__ rF,
    ushort* __restrict__ outbuf, int vert) {
  const int tid = threadIdx.x;
  const int lane = tid & 63, w = tid >> 6;
  const int l16 = lane & 15, kg = lane >> 4;
  const int rb = blockIdx.x, dir = (int)blockIdx.y;
  const int rowbase = rb << 4;

  __shared__ uint4 rs[2][4096];     // 2 x 64KB R slices [tile(64)][lane(64)]
  __shared__ ushort hbuf[2][4096];  // 2 x 8KB h, 16B-chunk XOR swizzle

  const uint4* rFd = rF + (size_t)dir * 32768;  // [64 tiles][8 kc][64 lanes]
  const uint4* zb = Zf + ((size_t)dir * 128 + rb) * 65536;
  const int cb0 = tid - lane;  // wave-uniform chunk base = w*64

  float cst[2][4];
#pragma unroll
  for (int q = 0; q < 2; ++q)
#pragma unroll
    for (int r = 0; r < 4; ++r) cst[q][r] = 0.f;

  uint4 zx[2][2];  // [q][p], components = gates; holds CURRENT step's zx
  {
    const int seq0 = dir ? 31 : 0;
#pragma unroll
    for (int q = 0; q < 2; ++q)
#pragma unroll
      for (int p = 0; p < 2; ++p)
        zx[q][p] = zb[(size_t)(((((seq0 << 1) + q) << 1) + p)) * 512 + tid];
  }
  // prologue: stage slice kc=0 into rs[0] (consumed first at t=1)
#pragma unroll
  for (int i = 0; i < 8; ++i) {
    const int T = w + (i << 3);
    load_lds16(rFd + ((size_t)(T << 3)) * 64 + lane,
               (uint4*)rs[0] + cb0 + (i << 9));
  }

  for (int t = 0; t < 32; ++t) {
    const ushort* hprev = hbuf[(t + 1) & 1];
    ushort* hnext = hbuf[t & 1];

    // ---- out-copy of h(t-1) ----
    if (t) {
      const int seqP = dir ? (32 - t) : (t - 1);
      const int row = tid >> 5, c4o = tid & 31;
      const uint4 v = *(const uint4*)((const char*)hprev + row * 512 +
                                      ((c4o ^ (row & 7)) << 4));
      const int n = rowbase + row, b = n >> 5, sp = n & 31;
      const int X = vert ? seqP : sp, Y = vert ? sp : seqP;
      *(uint4*)&outbuf[(((size_t)(b * 32 + X) * 32 + Y) << 9) + (dir << 8) +
                       (c4o << 3)] = v;
    }

    // ---- acc init = zx (both q) ----
    f32x4 acc[2][4];
#pragma unroll
    for (int q = 0; q < 2; ++q) {
#pragma unroll
      for (int g = 0; g < 4; ++g) {
        const unsigned int u0 = (g == 0) ? zx[q][0].x : (g == 1) ? zx[q][0].y
                                : (g == 2) ? zx[q][0].z : zx[q][0].w;
        const unsigned int u1 = (g == 0) ? zx[q][1].x : (g == 1) ? zx[q][1].y
                                : (g == 2) ? zx[q][1].z : zx[q][1].w;
        acc[q][g][0] = bf2f((ushort)(u0 & 0xffffu));
        acc[q][g][1] = bf2f((ushort)(u0 >> 16));
        acc[q][g][2] = bf2f((ushort)(u1 & 0xffffu));
        acc[q][g][3] = bf2f((ushort)(u1 >> 16));
      }
    }

    // ---- MFMA over kc slices (skipped at t=0: h(-1)=0) ----
    if (t) {
#pragma unroll
      for (int kc = 0; kc < 8; ++kc) {
        // issue next slice's DMA first (overlaps this iter's compute)
        if (kc < 7 || t < 31) {
          const int nk = (kc < 7) ? (kc + 1) : 0;
          const int nbuf = (kc + 1) & 1;
#pragma unroll
          for (int i = 0; i < 8; ++i) {
            const int T = w + (i << 3);
            load_lds16(rFd + ((size_t)((T << 3) + nk)) * 64 + lane,
                       (uint4*)rs[nbuf] + cb0 + (i << 9));
          }
        }
        // shared h-fragment (rows l16, k-chunk c4)
        const int c4 = (kc << 2) + kg;
        const uint4 a = *(const uint4*)((const char*)hprev + l16 * 512 +
                                        ((c4 ^ (l16 & 7)) << 4));
        const bf16x8 ab = __builtin_bit_cast(bf16x8, a);
#pragma unroll
        for (int q = 0; q < 2; ++q) {
#pragma unroll
          for (int g = 0; g < 4; ++g) {
            const int T = (g << 4) + (w << 1) + q;
            const bf16x8 bb =
                __builtin_bit_cast(bf16x8, rs[kc & 1][(T << 6) + lane]);
            acc[q][g] = mfma16(ab, bb, acc[q][g]);
          }
        }
        __syncthreads();  // next slice ready; this slice free for overwrite
      }
    }

    // ---- zx loads for next step (after all stage issues) ----
    if (t < 31) {
      const int seqn = dir ? (30 - t) : (t + 1);
#pragma unroll
      for (int q = 0; q < 2; ++q)
#pragma unroll
        for (int p = 0; p < 2; ++p)
          zx[q][p] = zb[(size_t)(((((seqn << 1) + q) << 1) + p)) * 512 + tid];
    }

    // ---- gate epilogue (both q) -> h(t) into LDS ----
#pragma unroll
    for (int q = 0; q < 2; ++q) {
      const int col = (w << 5) + (q << 4) + l16;
#pragma unroll
      for (int r = 0; r < 4; ++r) {
        const float zi = acc[q][0][r];
        const float zf = acc[q][1][r];
        const float zg = acc[q][2][r];
        const float zo = acc[q][3][r];
        const float cn = sigm(zf) * cst[q][r] + sigm(zi) * tanh_(zg);
        cst[q][r] = cn;
        const float hv = sigm(zo) * tanh_(cn);
        const int row = (kg << 2) + r;
        *(ushort*)((char*)hnext + row * 512 +
                   (((col >> 3) ^ (row & 7)) << 4) + ((col & 7) << 1)) =
            f2bf(hv);
      }
    }
    __syncthreads();  // h(t) complete; (t=0) also drains prologue slice DMA
  }

  // ---- final copy of h(31) ----
  {
    const int seqP = dir ? 0 : 31;
    const ushort* hl = hbuf[1];  // t=31 wrote hbuf[1]
    const int row = tid >> 5, c4o = tid & 31;
    const uint4 v = *(const uint4*)((const char*)hl + row * 512 +
                                    ((c4o ^ (row & 7)) << 4));
    const int n = rowbase + row, b = n >> 5, sp = n & 31;
    const int X = vert ? seqP : sp, Y = vert ? sp : seqP;
    *(uint4*)&outbuf[(((size_t)(b * 32 + X) * 32 + Y) << 9) + (dir << 8) +
                     (c4o << 3)] = v;
  }
}

// --------------------------------------------------------------------------
// Dual-dir horizontal projection, 8-wave blocks (512 thr): Zf[dir] =
// A @ kTh[dir]^T + bias[dir], fragment-major epilogue staged in one pass.
// Wave grid 4m x 2n over the 128x128 tile; per-wave 32x64 -> acc[2][4].
__global__ __launch_bounds__(512) void gemm_bt_dual(
    const ushort* __restrict__ A, const ushort* __restrict__ BT0,
    const ushort* __restrict__ BT1, const float* __restrict__ bias0,
    const float* __restrict__ bias1, uint4* __restrict__ Zf) {
  const int tid = threadIdx.x;
  const int lane = tid & 63, wid = tid >> 6;
  const int l16 = lane & 15, kg = lane >> 4;
  const int wr = wid >> 1, wc = wid & 1;  // 4m x 2n
  const int bid = blockIdx.x;
  const int xcd = bid & 7, lid = bid >> 3;
  const int m0 = ((xcd << 6) + (lid >> 4)) << 7;
  const int nb = lid & 15;
  const int dirq = nb >> 3;
  const int hc0 = (nb & 7) << 5;
  const ushort* BT = dirq ? BT1 : BT0;
  const float* bias = dirq ? bias1 : bias0;
  uint4* Cz = Zf + (size_t)dirq * 8388608;

  union SM {
    struct { uint4 A[128][8]; uint4 B[128][8]; } k;
    ushort eh[128][136];
  };
  __shared__ SM sm;

  f32x4 acc[2][4];
#pragma unroll
  for (int mt = 0; mt < 2; ++mt)
#pragma unroll
    for (int nt = 0; nt < 4; ++nt) acc[mt][nt] = (f32x4){0.f, 0.f, 0.f, 0.f};

  for (int k0 = 0; k0 < 512; k0 += 64) {
#pragma unroll
    for (int c = 0; c < 2; ++c) {
      const int cid = (wid << 7) + (c << 6) + lane;  // 0..1023
      const int row = cid >> 3, ch = cid & 7;
      const int sch = ch ^ (row & 7);
      const int brow = ((row >> 5) << 8) + hc0 + (row & 31);
      load_lds16(A + (size_t)(m0 + row) * 512 + k0 + (sch << 3),
                 (uint4*)sm.k.A + (cid - lane));
      load_lds16(BT + (size_t)brow * 512 + k0 + (sch << 3),
                 (uint4*)sm.k.B + (cid - lane));
    }
    __syncthreads();
#pragma unroll
    for (int kk = 0; kk < 2; ++kk) {
      const int q = (kk << 2) + kg;
      bf16x8 a[2], b[4];
#pragma unroll
      for (int mt = 0; mt < 2; ++mt) {
        const int rr = (wr << 5) + (mt << 4) + l16;
        a[mt] = __builtin_bit_cast(bf16x8, sm.k.A[rr][q ^ (rr & 7)]);
      }
#pragma unroll
      for (int nt = 0; nt < 4; ++nt) {
        const int rr = (wc << 6) + (nt << 4) + l16;
        b[nt] = __builtin_bit_cast(bf16x8, sm.k.B[rr][q ^ (rr & 7)]);
      }
#pragma unroll
      for (int mt = 0; mt < 2; ++mt)
#pragma unroll
        for (int nt = 0; nt < 4; ++nt)
          acc[mt][nt] = mfma16(a[mt], b[nt], acc[mt][nt]);
    }
    __syncthreads();
  }

  float bn[4];
#pragma unroll
  for (int nt = 0; nt < 4; ++nt) {
    const int lcol = (wc << 6) + (nt << 4) + l16;
    bn[nt] = bias[((lcol >> 5) << 8) + hc0 + (lcol & 31)];
  }

  // stage ALL 128 rows at once (eh aliases k stage; all LDS reads done)
#pragma unroll
  for (int mt = 0; mt < 2; ++mt) {
#pragma unroll
    for (int nt = 0; nt < 4; ++nt) {
      const int col = (wc << 6) + (nt << 4) + l16;
#pragma unroll
      for (int r = 0; r < 4; ++r) {
        const int rowl = (wr << 5) + (mt << 4) + (kg << 2) + r;
        sm.eh[rowl][col] = f2bf(acc[mt][nt][r] + bn[nt]);
      }
    }
  }
  __syncthreads();

#pragma unroll
  for (int h = 0; h < 2; ++h) {
    // n-pair n2 = (m0>>6)+h covers local rows [h*64, h*64+64)
    const int n_a = ((m0 >> 6) + h) << 1;
    const int rbz = n_a >> 4;
    const int n2l = (n_a & 15) >> 1;
    const int kgz = n2l >> 1, pz = n2l & 1;
#pragma unroll
    for (int it = 0; it < 2; ++it) {
      const int e = tid + (it << 9);  // 0..1023
      const int seq = e >> 5, hl = e & 31;
      const int qv = hl >> 4, l16v = hl & 15;
      const int wz = (hc0 + hl) >> 5;
      const int tidz = (wz << 6) + (kgz << 4) + l16v;
      uint4 o;
      o.x = (unsigned int)sm.eh[(h << 6) + seq][hl] |
            ((unsigned int)sm.eh[(h << 6) + 32 + seq][hl] << 16);
      o.y = (unsigned int)sm.eh[(h << 6) + seq][32 + hl] |
            ((unsigned int)sm.eh[(h << 6) + 32 + seq][32 + hl] << 16);
      o.z = (unsigned int)sm.eh[(h << 6) + seq][64 + hl] |
            ((unsigned int)sm.eh[(h << 6) + 32 + seq][64 + hl] << 16);
      o.w = (unsigned int)sm.eh[(h << 6) + seq][96 + hl] |
            ((unsigned int)sm.eh[(h << 6) + 32 + seq][96 + hl] << 16);
      Cz[(size_t)rbz * 65536 + (size_t)((((seq << 1) + qv) << 1) + pz) * 512 +
         tidz] = o;
    }
  }
}

// --------------------------------------------------------------------------
// Dense, 8-wave blocks (512 thr): out = relu(A @ WdT^T + bd), f32 stores.
__global__ __launch_bounds__(512) void gemm_dense(
    const ushort* __restrict__ A, const ushort* __restrict__ BT,
    const float* __restrict__ bias, float* __restrict__ out) {
  const int tid = threadIdx.x;
  const int lane = tid & 63, wid = tid >> 6;
  const int l16 = lane & 15, kg = lane >> 4;
  const int wr = wid >> 1, wc = wid & 1;  // 4m x 2n
  const int bid = blockIdx.x;
  const int xcd = bid & 7, lid = bid >> 3;
  const int m0 = ((xcd << 6) + (lid >> 3)) << 7;
  const int n0 = (lid & 7) << 7;

  union SM {
    struct { uint4 A[128][8]; uint4 B[128][8]; } k;
    float ef[64][132];
  };
  __shared__ SM sm;

  f32x4 acc[2][4];
#pragma unroll
  for (int mt = 0; mt < 2; ++mt)
#pragma unroll
    for (int nt = 0; nt < 4; ++nt) acc[mt][nt] = (f32x4){0.f, 0.f, 0.f, 0.f};

  for (int k0 = 0; k0 < 512; k0 += 64) {
#pragma unroll
    for (int c = 0; c < 2; ++c) {
      const int cid = (wid << 7) + (c << 6) + lane;  // 0..1023
      const int row = cid >> 3, ch = cid & 7;
      const int sch = ch ^ (row & 7);
      load_lds16(A + (size_t)(m0 + row) * 512 + k0 + (sch << 3),
                 (uint4*)sm.k.A + (cid - lane));
      load_lds16(BT + (size_t)(n0 + row) * 512 + k0 + (sch << 3),
                 (uint4*)sm.k.B + (cid - lane));
    }
    __syncthreads();
#pragma unroll
    for (int kk = 0; kk < 2; ++kk) {
      const int q = (kk << 2) + kg;
      bf16x8 a[2], b[4];
#pragma unroll
      for (int mt = 0; mt < 2; ++mt) {
        const int rr = (wr << 5) + (mt << 4) + l16;
        a[mt] = __builtin_bit_cast(bf16x8, sm.k.A[rr][q ^ (rr & 7)]);
      }
#pragma unroll
      for (int nt = 0; nt < 4; ++nt) {
        const int rr = (wc << 6) + (nt << 4) + l16;
        b[nt] = __builtin_bit_cast(bf16x8, sm.k.B[rr][q ^ (rr & 7)]);
      }
#pragma unroll
      for (int mt = 0; mt < 2; ++mt)
#pragma unroll
        for (int nt = 0; nt < 4; ++nt)
          acc[mt][nt] = mfma16(a[mt], b[nt], acc[mt][nt]);
    }
    __syncthreads();
  }

  float bn[4];
#pragma unroll
  for (int nt = 0; nt < 4; ++nt)
    bn[nt] = bias[n0 + (wc << 6) + (nt << 4) + l16];

#pragma unroll
  for (int h = 0; h < 2; ++h) {
    __syncthreads();
    if ((wr >> 1) == h) {  // waves wr in {2h, 2h+1} own rows [h*64, +64)
#pragma unroll
      for (int mt = 0; mt < 2; ++mt) {
#pragma unroll
        for (int nt = 0; nt < 4; ++nt) {
          const int col = (wc << 6) + (nt << 4) + l16;
#pragma unroll
          for (int r = 0; r < 4; ++r) {
            const int rowl = ((wr & 1) << 5) + (mt << 4) + (kg << 2) + r;
            sm.ef[rowl][col] = fmaxf(acc[mt][nt][r] + bn[nt], 0.f);
          }
        }
      }
    }
    __syncthreads();
#pragma unroll
    for (int it = 0; it < 4; ++it) {
      const int c = tid + (it << 9);  // 0..2047
      const int row = c >> 5, co = (c & 31) << 2;
      const f32x4 v = *(const f32x4*)&sm.ef[row][co];
      __builtin_nontemporal_store(
          v, (f32x4*)(out + (size_t)(m0 + (h << 6) + row) * 1024 + n0 + co));
    }
  }
}

}  // namespace

extern "C" void kernel_launch(void* const* d_in, const int* in_sizes, int n_in,
                              void* d_out, int out_size, void* d_ws, size_t ws_size,
                              hipStream_t stream) {
  (void)in_sizes; (void)n_in; (void)out_size; (void)ws_size;
  const float* x    = (const float*)d_in[0];
  const float* k_ud = (const float*)d_in[1];
  const float* r_ud = (const float*)d_in[2];
  const float* b_ud = (const float*)d_in[3];
  const float* k_du = (const float*)d_in[4];
  const float* r_du = (const float*)d_in[5];
  const float* b_du = (const float*)d_in[6];
  const float* k_lr = (const float*)d_in[7];
  const float* r_lr = (const float*)d_in[8];
  const float* b_lr = (const float*)d_in[9];
  const float* k_rl = (const float*)d_in[10];
  const float* r_rl = (const float*)d_in[11];
  const float* b_rl = (const float*)d_in[12];
  const float* Wd   = (const float*)d_in[13];
  const float* bd   = (const float*)d_in[14];

  ushort* W    = (ushort*)d_ws;
  ushort* Z    = W;                      // Zf: 2*128*65536 uint4 = 268 MB
  ushort* vbuf = Z + 134217728;          // [64][32][32][512]    33554432
  ushort* rF   = vbuf + 33554432;        // [4][64][8][64][8]     1048576
  ushort* kTh  = rF + 1048576;           // [2][1024][512]        1048576
  ushort* WdT  = kTh + 1048576;          // [1024][512]            524288
  uint4* Zf = (uint4*)Z;

  // ---- weight prep (merged launches) ----
  rfrag_all<<<dim3(128, 4), 256, 0, stream>>>(r_ud, r_du, r_lr, r_rl, rF);
  transpose_all<<<dim3(2048, 3), 256, 0, stream>>>(k_lr, k_rl, Wd, kTh,
                                                   kTh + 524288, WdT);

  // ---- vertical input projection (K=12) -> fragment-major Zf ----
  zxv3_kernel<<<dim3(16, 64, 2), 256, 0, stream>>>(x, k_ud, b_ud, k_du, b_du,
                                                   Zf);

  // ---- vertical sweep ----
  lstm_sweep12<<<dim3(128, 2), 512, 0, stream>>>(Zf, (const uint4*)rF, vbuf,
                                                 1);

  // ---- horizontal input projection (both dirs, one launch, 8-wave) ----
  gemm_bt_dual<<<8192, 512, 0, stream>>>(vbuf, kTh, kTh + 524288, b_lr, b_rl,
                                         Zf);

  // ---- horizontal sweep (writes hfin over vbuf; reads only Zf) ----
  lstm_sweep12<<<dim3(128, 2), 512, 0, stream>>>(
      Zf, (const uint4*)(rF + 524288), vbuf, 0);

  // ---- dense + relu (8-wave) ----
  gemm_dense<<<4096, 512, 0, stream>>>(vbuf, WdT, bd, (float*)d_out);
}

// Round 19
// 716.407 us; speedup vs baseline: 1.2636x; 1.2636x over previous
//
#include <hip/hip_runtime.h>
#include <math.h>
#include <stddef.h>
#include <stdint.h>

// ---------------------------------------------------------------------------
// ReNet: patches -> vert bidir LSTM -> horiz bidir LSTM -> dense+relu
// B=64, I=J=32, D=12, HID=256, FC=1024.
// Round 19: sweep reverted to sweep7 (254us local optimum; r18's LDS-DMA
// variant regressed). zxv3 ELIMINATED: vertical zx folded into the sweep as
// an MFMA with bias-augmented k-fragments (p extended with constant-1 at
// k=12, bias in kfrag row 12). Horizontal path byte-identical to r17.
// ---------------------------------------------------------------------------

namespace {

typedef __bf16 bf16x8 __attribute__((ext_vector_type(8)));
typedef float f32x4 __attribute__((ext_vector_type(4)));
typedef __attribute__((address_space(1))) unsigned int as1_uint;
typedef __attribute__((address_space(3))) unsigned int as3_uint;

__device__ __forceinline__ float bf2f(ushort u) {
  return __builtin_bit_cast(float, (unsigned int)u << 16);
}
__device__ __forceinline__ ushort f2bf(float f) {
  unsigned int u = __builtin_bit_cast(unsigned int, f);
  u += 0x7fffu + ((u >> 16) & 1u);
  return (ushort)(u >> 16);
}
__device__ __forceinline__ unsigned int packbf(float a, float b) {
  return (unsigned int)f2bf(a) | ((unsigned int)f2bf(b) << 16);
}
__device__ __forceinline__ float sigm(float x) {
  return __fdividef(1.f, 1.f + __expf(-x));
}
__device__ __forceinline__ float tanh_(float x) {
  return 2.f * sigm(2.f * x) - 1.f;
}
__device__ __forceinline__ f32x4 mfma16(bf16x8 a, bf16x8 b, f32x4 c) {
  return __builtin_amdgcn_mfma_f32_16x16x32_bf16(a, b, c, 0, 0, 0);
}
__device__ __forceinline__ void load_lds16(const void* g, void* l) {
  __builtin_amdgcn_global_load_lds((const as1_uint*)g, (as3_uint*)l, 16, 0, 0);
}

// Zf fragment-major layout, per (dir, rb16) [rb16 = 16-row group, 0..127]:
// 65536 uint4. index = ((seq*2 + q)*2 + p)*512 + tidz ; components = gates.
// uint packs bf16 local rows (2*n2l, 2*n2l+1), n2l = kg*2+p (0..7),
// tidz = w*64 + kg*16 + l16, hcol = w*32 + q*16 + l16.
// dir stride = 128*65536 uint4. (Horizontal sweep only.)

// --------------------------------------------------------------------------
// merged transpose: f32 [512][1024] -> bf16 [1024][512], 3 srcs by blockIdx.y
__global__ __launch_bounds__(256) void transpose_all(
    const float* __restrict__ s0, const float* __restrict__ s1,
    const float* __restrict__ s2, ushort* __restrict__ d0,
    ushort* __restrict__ d1, ushort* __restrict__ d2) {
  const int which = blockIdx.y;
  const float* in = (which == 0) ? s0 : (which == 1) ? s1 : s2;
  ushort* out = (which == 0) ? d0 : (which == 1) ? d1 : d2;
  const int idx = blockIdx.x * 256 + threadIdx.x;  // 524288 ids
  const int n = idx >> 9, k = idx & 511;
  out[idx] = f2bf(in[k * 1024 + n]);
}

// --------------------------------------------------------------------------
// merged rfrag: repack r [256][1024] f32 -> MFMA B-fragment-major bf16,
// 4 srcs by blockIdx.y.
__global__ __launch_bounds__(256) void rfrag_all(
    const float* __restrict__ r0, const float* __restrict__ r1,
    const float* __restrict__ r2, const float* __restrict__ r3,
    ushort* __restrict__ out) {
  const int which = blockIdx.y;
  const float* r = (which == 0) ? r0 : (which == 1) ? r1 : (which == 2) ? r2 : r3;
  ushort* o = out + (size_t)which * 262144;
  const int id = blockIdx.x * 256 + threadIdx.x;  // 32768 ids
  const int lane = id & 63, kc = (id >> 6) & 7, tile = id >> 9;
  const int kbase = (kc << 5) + ((lane >> 4) << 3);
  const int col = (tile << 4) + (lane & 15);
  ushort tmp[8];
#pragma unroll
  for (int j = 0; j < 8; ++j) tmp[j] = f2bf(r[(size_t)(kbase + j) * 1024 + col]);
  *(uint4*)&o[(size_t)id << 3] = *(const uint4*)tmp;
}

// --------------------------------------------------------------------------
// Vertical k-fragments, bias-augmented: out[dir][tile(64)][lane(64)][8] bf16.
// elem j: kidx = (lane>>4)*8+j; col = tile*16+(lane&15);
// value = kidx<12 ? k[kidx][col] : (kidx==12 ? bias[col] : 0).
__global__ __launch_bounds__(256) void kfragv_kernel(
    const float* __restrict__ k0, const float* __restrict__ b0,
    const float* __restrict__ k1, const float* __restrict__ b1,
    ushort* __restrict__ out) {
  const int dir = blockIdx.y;
  const int idx = blockIdx.x * 256 + threadIdx.x;  // 0..4095
  const int lane = idx & 63;
  const int kbase = (lane >> 4) << 3;
  const int col = ((idx >> 6) << 4) + (lane & 15);
  const float* kw = dir ? k1 : k0;
  const float* bw = dir ? b1 : b0;
  ushort tmp[8];
#pragma unroll
  for (int j = 0; j < 8; ++j) {
    const int kidx = kbase + j;
    const float v = (kidx < 12) ? kw[kidx * 1024 + col]
                  : (kidx == 12) ? bw[col] : 0.f;
    tmp[j] = f2bf(v);
  }
  *(uint4*)&out[((size_t)dir * 4096 + idx) << 3] = *(const uint4*)tmp;
}

// --------------------------------------------------------------------------
// VERTICAL LSTM sweep: sweep7 structure, but zx computed in-kernel via MFMA
// (p-patch staged per step, kfrag LDS-resident). No Zf involvement.
// Grid (128 rowblk, 2 dir) = 256 blocks, 512 thr (8 waves).
__global__ __launch_bounds__(512) void lstm_sweepV(
    const float* __restrict__ x, const ushort* __restrict__ kfragV,
    const uint4* __restrict__ rF, ushort* __restrict__ outbuf) {
  const int tid = threadIdx.x;
  const int lane = tid & 63, w = tid >> 6;
  const int l16 = lane & 15, kg = lane >> 4;
  const int rb = blockIdx.x, dir = (int)blockIdx.y;
  const int rowbase = rb << 4;
  const int bb = rb >> 1;            // batch index (constant per block)
  const int jbase = (rb & 1) << 4;   // j = jbase + row

  __shared__ ushort hbuf[2][4096];   // 2 x 8KB h, 16B-chunk XOR swizzle
  __shared__ uint4 kfr[4096];        // 64KB k-fragments [tile][lane]
  __shared__ ushort pb[2][512];      // 2 x [16 rows][32 k] bf16 patches

  const uint4* rFd = rF + (size_t)dir * 32768;

  // ---- prologue ----
  // pb constants: k=12 -> 1.0, k=13..31 -> 0 (both parities)
  for (int e = tid; e < 640; e += 512) {
    const int par = e / 320, rest = e - par * 320;
    const int row = rest / 20, c = 12 + rest % 20;
    pb[par][(row << 5) + c] = (c == 12) ? (ushort)0x3F80 : (ushort)0;
  }
  // p(0) gather
  if (tid < 192) {
    const int row = tid / 12, d = tid - row * 12;
    const int pr = d / 6, rem = d - pr * 6, pc = rem / 3, c = rem - pc * 3;
    const int i0 = dir ? 31 : 0;
    const float v = x[((size_t)((bb * 64 + (i0 << 1) + pr) * 64) +
                       ((jbase + row) << 1) + pc) * 3 + c];
    pb[0][(row << 5) + d] = f2bf(v);
  }
  // kfrag DMA (64KB, linear)
#pragma unroll
  for (int i = 0; i < 8; ++i)
    load_lds16((const uint4*)kfragV + (size_t)dir * 4096 + tid + (i << 9),
               kfr + (tid - lane) + (i << 9));
  __syncthreads();

  float cst[2][4];
#pragma unroll
  for (int q = 0; q < 2; ++q)
#pragma unroll
    for (int r = 0; r < 4; ++r) cst[q][r] = 0.f;

  for (int t = 0; t < 32; ++t) {
    const int seq = dir ? (31 - t) : t;
    const ushort* hprev = hbuf[(t + 1) & 1];
    ushort* hnext = hbuf[t & 1];

    // ---- overlapped out-copy of h(t-1) ----
    if (t) {
      const int seqP = dir ? (32 - t) : (t - 1);
      const int row = tid >> 5, c4o = tid & 31;
      const uint4 v = *(const uint4*)((const char*)hprev + row * 512 +
                                      ((c4o ^ (row & 7)) << 4));
      const int n = rowbase + row, b = n >> 5, sp = n & 31;
      *(uint4*)&outbuf[(((size_t)(b * 32 + seqP) * 32 + sp) << 9) +
                       (dir << 8) + (c4o << 3)] = v;
    }

    // ---- issue p(t+1) global loads (consumed at epilogue) ----
    float pv = 0.f;
    if (t < 31 && tid < 192) {
      const int row = tid / 12, d = tid - row * 12;
      const int pr = d / 6, rem = d - pr * 6, pc = rem / 3, c = rem - pc * 3;
      const int iN = dir ? (30 - t) : (t + 1);
      pv = x[((size_t)((bb * 64 + (iN << 1) + pr) * 64) +
              ((jbase + row) << 1) + pc) * 3 + c];
    }

    // ---- acc init = zx via MFMA: p_frag x kfrag (bias folded) ----
    const bf16x8 pf = __builtin_bit_cast(
        bf16x8, *(const uint4*)&pb[t & 1][(l16 << 5) + (kg << 3)]);
    f32x4 acc[2][4];
#pragma unroll
    for (int q = 0; q < 2; ++q) {
#pragma unroll
      for (int g = 0; g < 4; ++g) {
        const int tile = (g << 4) + (w << 1) + q;
        const bf16x8 kb = __builtin_bit_cast(bf16x8, kfr[(tile << 6) + lane]);
        acc[q][g] = mfma16(pf, kb, (f32x4){0.f, 0.f, 0.f, 0.f});
      }
    }

    // ---- MFMA: acc += h(t-1) @ R, bfr kc-ring (sweep7 structure) ----
    if (t) {
#pragma unroll
      for (int q = 0; q < 2; ++q) {
        uint4 bfr[2][4];
#pragma unroll
        for (int g = 0; g < 4; ++g)
          bfr[0][g] = rFd[(size_t)(((g << 4) + (w << 1) + q) << 3) * 64 + lane];
#pragma unroll
        for (int kc = 0; kc < 8; ++kc) {
          const int cur = kc & 1;
          if (kc < 7) {
#pragma unroll
            for (int g = 0; g < 4; ++g)
              bfr[cur ^ 1][g] =
                  rFd[((size_t)(((g << 4) + (w << 1) + q) << 3) + kc + 1) * 64 +
                      lane];
          }
          const int c4 = (kc << 2) + kg;
          const uint4 a = *(const uint4*)((const char*)hprev + l16 * 512 +
                                          ((c4 ^ (l16 & 7)) << 4));
          const bf16x8 ab = __builtin_bit_cast(bf16x8, a);
#pragma unroll
          for (int g = 0; g < 4; ++g)
            acc[q][g] =
                mfma16(ab, __builtin_bit_cast(bf16x8, bfr[cur][g]), acc[q][g]);
        }
      }
    }

    // ---- write p(t+1) into LDS (covered by end-of-step barrier) ----
    if (t < 31 && tid < 192) {
      const int row = tid / 12, d = tid - row * 12;
      pb[(t + 1) & 1][(row << 5) + d] = f2bf(pv);
    }

    // ---- gate epilogue (both q) -> h(t) into LDS ----
#pragma unroll
    for (int q = 0; q < 2; ++q) {
      const int col = (w << 5) + (q << 4) + l16;
#pragma unroll
      for (int r = 0; r < 4; ++r) {
        const float zi = acc[q][0][r];
        const float zf = acc[q][1][r];
        const float zg = acc[q][2][r];
        const float zo = acc[q][3][r];
        const float cn = sigm(zf) * cst[q][r] + sigm(zi) * tanh_(zg);
        cst[q][r] = cn;
        const float hv = sigm(zo) * tanh_(cn);
        const int row = (kg << 2) + r;
        *(ushort*)((char*)hnext + row * 512 +
                   (((col >> 3) ^ (row & 7)) << 4) + ((col & 7) << 1)) =
            f2bf(hv);
      }
    }
    __syncthreads();
  }

  // ---- final copy of h(31) ----
  {
    const int seqP = dir ? 0 : 31;
    const ushort* hl = hbuf[1];
    const int row = tid >> 5, c4o = tid & 31;
    const uint4 v = *(const uint4*)((const char*)hl + row * 512 +
                                    ((c4o ^ (row & 7)) << 4));
    const int n = rowbase + row, b = n >> 5, sp = n & 31;
    *(uint4*)&outbuf[(((size_t)(b * 32 + seqP) * 32 + sp) << 9) + (dir << 8) +
                     (c4o << 3)] = v;
  }
}

// --------------------------------------------------------------------------
// HORIZONTAL LSTM sweep (r11/r17 sweep7, verbatim; reads Zf).
__global__ __launch_bounds__(512) void lstm_sweep7(
    const uint4* __restrict__ Zf, const uint4* __restrict__ rF,
    ushort* __restrict__ outbuf, int vert) {
  const int tid = threadIdx.x;
  const int lane = tid & 63, w = tid >> 6;
  const int l16 = lane & 15, kg = lane >> 4;
  const int rb = blockIdx.x, dir = (int)blockIdx.y;
  const int rowbase = rb << 4;

  __shared__ ushort hbuf[2][4096];  // 2 x 8 KB, 16B-chunk XOR swizzle

  const uint4* rFd = rF + (size_t)dir * 32768;
  const uint4* zb = Zf + ((size_t)dir * 128 + rb) * 65536;

  float cst[2][4];
#pragma unroll
  for (int q = 0; q < 2; ++q)
#pragma unroll
    for (int r = 0; r < 4; ++r) cst[q][r] = 0.f;

  uint4 zA[2], zB[2];
  {
    const int seq0 = dir ? 31 : 0;
    zA[0] = zb[(size_t)(seq0 << 2) * 512 + tid];
    zA[1] = zb[(size_t)((seq0 << 2) + 1) * 512 + tid];
  }

  for (int t = 0; t < 32; ++t) {
    const ushort* hprev = hbuf[(t + 1) & 1];
    ushort* hnext = hbuf[t & 1];

    if (t) {
      const int seqP = dir ? (32 - t) : (t - 1);
      const int row = tid >> 5, c4 = tid & 31;
      const uint4 v = *(const uint4*)((const char*)hprev + row * 512 +
                                      ((c4 ^ (row & 7)) << 4));
      const int n = rowbase + row, b = n >> 5, sp = n & 31;
      const int X = vert ? seqP : sp, Y = vert ? sp : seqP;
      *(uint4*)&outbuf[(((size_t)(b * 32 + X) * 32 + Y) << 9) + (dir << 8) +
                       (c4 << 3)] = v;
    }

#pragma unroll
    for (int q = 0; q < 2; ++q) {
      uint4(&zc)[2] = (q == 0) ? zA : zB;
      uint4(&zn)[2] = (q == 0) ? zB : zA;

      f32x4 acc[4];
#pragma unroll
      for (int g = 0; g < 4; ++g) {
        const unsigned int u0 = (g == 0) ? zc[0].x : (g == 1) ? zc[0].y
                                : (g == 2) ? zc[0].z : zc[0].w;
        const unsigned int u1 = (g == 0) ? zc[1].x : (g == 1) ? zc[1].y
                                : (g == 2) ? zc[1].z : zc[1].w;
        acc[g][0] = bf2f((ushort)(u0 & 0xffffu));
        acc[g][1] = bf2f((ushort)(u0 >> 16));
        acc[g][2] = bf2f((ushort)(u1 & 0xffffu));
        acc[g][3] = bf2f((ushort)(u1 >> 16));
      }

      if (t) {
        uint4 bfr[2][4];
#pragma unroll
        for (int g = 0; g < 4; ++g)
          bfr[0][g] = rFd[(size_t)(((g << 4) + (w << 1) + q) << 3) * 64 + lane];
#pragma unroll
        for (int kc = 0; kc < 8; ++kc) {
          const int cur = kc & 1;
          if (kc < 7) {
#pragma unroll
            for (int g = 0; g < 4; ++g)
              bfr[cur ^ 1][g] =
                  rFd[((size_t)(((g << 4) + (w << 1) + q) << 3) + kc + 1) * 64 +
                      lane];
          }
          const int c4 = (kc << 2) + kg;
          const uint4 a = *(const uint4*)((const char*)hprev + l16 * 512 +
                                          ((c4 ^ (l16 & 7)) << 4));
          const bf16x8 ab = __builtin_bit_cast(bf16x8, a);
#pragma unroll
          for (int g = 0; g < 4; ++g)
            acc[g] = mfma16(ab, __builtin_bit_cast(bf16x8, bfr[cur][g]), acc[g]);
        }
      }

      if (t < 31 || q == 0) {
        const int tn = q ? (t + 1) : t;
        const int qn = q ^ 1;
        const int seqn = dir ? (31 - tn) : tn;
        zn[0] = zb[(size_t)(((seqn << 1) + qn) << 1) * 512 + tid];
        zn[1] = zb[(size_t)((((seqn << 1) + qn) << 1) + 1) * 512 + tid];
      }

      const int col = (w << 5) + (q << 4) + l16;
#pragma unroll
      for (int r = 0; r < 4; ++r) {
        const float zi = acc[0][r];
        const float zf = acc[1][r];
        const float zg = acc[2][r];
        const float zo = acc[3][r];
        const float cn = sigm(zf) * cst[q][r] + sigm(zi) * tanh_(zg);
        cst[q][r] = cn;
        const float hv = sigm(zo) * tanh_(cn);
        const int row = (kg << 2) + r;
        *(ushort*)((char*)hnext + row * 512 +
                   (((col >> 3) ^ (row & 7)) << 4) + ((col & 7) << 1)) =
            f2bf(hv);
      }
    }
    __syncthreads();
  }

  {
    const int seqP = dir ? 0 : 31;
    const ushort* hl = hbuf[1];
    const int row = tid >> 5, c4 = tid & 31;
    const uint4 v = *(const uint4*)((const char*)hl + row * 512 +
                                    ((c4 ^ (row & 7)) << 4));
    const int n = rowbase + row, b = n >> 5, sp = n & 31;
    const int X = vert ? seqP : sp, Y = vert ? sp : seqP;
    *(uint4*)&outbuf[(((size_t)(b * 32 + X) * 32 + Y) << 9) + (dir << 8) +
                     (c4 << 3)] = v;
  }
}

// --------------------------------------------------------------------------
// Dual-dir horizontal projection, 8-wave blocks (512 thr): Zf[dir] =
// A @ kTh[dir]^T + bias[dir], fragment-major epilogue staged in one pass.
__global__ __launch_bounds__(512) void gemm_bt_dual(
    const ushort* __restrict__ A, const ushort* __restrict__ BT0,
    const ushort* __restrict__ BT1, const float* __restrict__ bias0,
    const float* __restrict__ bias1, uint4* __restrict__ Zf) {
  const int tid = threadIdx.x;
  const int lane = tid & 63, wid = tid >> 6;
  const int l16 = lane & 15, kg = lane >> 4;
  const int wr = wid >> 1, wc = wid & 1;  // 4m x 2n
  const int bid = blockIdx.x;
  const int xcd = bid & 7, lid = bid >> 3;
  const int m0 = ((xcd << 6) + (lid >> 4)) << 7;
  const int nb = lid & 15;
  const int dirq = nb >> 3;
  const int hc0 = (nb & 7) << 5;
  const ushort* BT = dirq ? BT1 : BT0;
  const float* bias = dirq ? bias1 : bias0;
  uint4* Cz = Zf + (size_t)dirq * 8388608;

  union SM {
    struct { uint4 A[128][8]; uint4 B[128][8]; } k;
    ushort eh[128][136];
  };
  __shared__ SM sm;

  f32x4 acc[2][4];
#pragma unroll
  for (int mt = 0; mt < 2; ++mt)
#pragma unroll
    for (int nt = 0; nt < 4; ++nt) acc[mt][nt] = (f32x4){0.f, 0.f, 0.f, 0.f};

  for (int k0 = 0; k0 < 512; k0 += 64) {
#pragma unroll
    for (int c = 0; c < 2; ++c) {
      const int cid = (wid << 7) + (c << 6) + lane;
      const int row = cid >> 3, ch = cid & 7;
      const int sch = ch ^ (row & 7);
      const int brow = ((row >> 5) << 8) + hc0 + (row & 31);
      load_lds16(A + (size_t)(m0 + row) * 512 + k0 + (sch << 3),
                 (uint4*)sm.k.A + (cid - lane));
      load_lds16(BT + (size_t)brow * 512 + k0 + (sch << 3),
                 (uint4*)sm.k.B + (cid - lane));
    }
    __syncthreads();
#pragma unroll
    for (int kk = 0; kk < 2; ++kk) {
      const int q = (kk << 2) + kg;
      bf16x8 a[2], b[4];
#pragma unroll
      for (int mt = 0; mt < 2; ++mt) {
        const int rr = (wr << 5) + (mt << 4) + l16;
        a[mt] = __builtin_bit_cast(bf16x8, sm.k.A[rr][q ^ (rr & 7)]);
      }
#pragma unroll
      for (int nt = 0; nt < 4; ++nt) {
        const int rr = (wc << 6) + (nt << 4) + l16;
        b[nt] = __builtin_bit_cast(bf16x8, sm.k.B[rr][q ^ (rr & 7)]);
      }
#pragma unroll
      for (int mt = 0; mt < 2; ++mt)
#pragma unroll
        for (int nt = 0; nt < 4; ++nt)
          acc[mt][nt] = mfma16(a[mt], b[nt], acc[mt][nt]);
    }
    __syncthreads();
  }

  float bn[4];
#pragma unroll
  for (int nt = 0; nt < 4; ++nt) {
    const int lcol = (wc << 6) + (nt << 4) + l16;
    bn[nt] = bias[((lcol >> 5) << 8) + hc0 + (lcol & 31)];
  }

#pragma unroll
  for (int mt = 0; mt < 2; ++mt) {
#pragma unroll
    for (int nt = 0; nt < 4; ++nt) {
      const int col = (wc << 6) + (nt << 4) + l16;
#pragma unroll
      for (int r = 0; r < 4; ++r) {
        const int rowl = (wr << 5) + (mt << 4) + (kg << 2) + r;
        sm.eh[rowl][col] = f2bf(acc[mt][nt][r] + bn[nt]);
      }
    }
  }
  __syncthreads();

#pragma unroll
  for (int h = 0; h < 2; ++h) {
    const int n_a = ((m0 >> 6) + h) << 1;
    const int rbz = n_a >> 4;
    const int n2l = (n_a & 15) >> 1;
    const int kgz = n2l >> 1, pz = n2l & 1;
#pragma unroll
    for (int it = 0; it < 2; ++it) {
      const int e = tid + (it << 9);
      const int seq = e >> 5, hl = e & 31;
      const int qv = hl >> 4, l16v = hl & 15;
      const int wz = (hc0 + hl) >> 5;
      const int tidz = (wz << 6) + (kgz << 4) + l16v;
      uint4 o;
      o.x = (unsigned int)sm.eh[(h << 6) + seq][hl] |
            ((unsigned int)sm.eh[(h << 6) + 32 + seq][hl] << 16);
      o.y = (unsigned int)sm.eh[(h << 6) + seq][32 + hl] |
            ((unsigned int)sm.eh[(h << 6) + 32 + seq][32 + hl] << 16);
      o.z = (unsigned int)sm.eh[(h << 6) + seq][64 + hl] |
            ((unsigned int)sm.eh[(h << 6) + 32 + seq][64 + hl] << 16);
      o.w = (unsigned int)sm.eh[(h << 6) + seq][96 + hl] |
            ((unsigned int)sm.eh[(h << 6) + 32 + seq][96 + hl] << 16);
      Cz[(size_t)rbz * 65536 + (size_t)((((seq << 1) + qv) << 1) + pz) * 512 +
         tidz] = o;
    }
  }
}

// --------------------------------------------------------------------------
// Dense, 8-wave blocks (512 thr): out = relu(A @ WdT^T + bd), f32 stores.
__global__ __launch_bounds__(512) void gemm_dense(
    const ushort* __restrict__ A, const ushort* __restrict__ BT,
    const float* __restrict__ bias, float* __restrict__ out) {
  const int tid = threadIdx.x;
  const int lane = tid & 63, wid = tid >> 6;
  const int l16 = lane & 15, kg = lane >> 4;
  const int wr = wid >> 1, wc = wid & 1;
  const int bid = blockIdx.x;
  const int xcd = bid & 7, lid = bid >> 3;
  const int m0 = ((xcd << 6) + (lid >> 3)) << 7;
  const int n0 = (lid & 7) << 7;

  union SM {
    struct { uint4 A[128][8]; uint4 B[128][8]; } k;
    float ef[64][132];
  };
  __shared__ SM sm;

  f32x4 acc[2][4];
#pragma unroll
  for (int mt = 0; mt < 2; ++mt)
#pragma unroll
    for (int nt = 0; nt < 4; ++nt) acc[mt][nt] = (f32x4){0.f, 0.f, 0.f, 0.f};

  for (int k0 = 0; k0 < 512; k0 += 64) {
#pragma unroll
    for (int c = 0; c < 2; ++c) {
      const int cid = (wid << 7) + (c << 6) + lane;
      const int row = cid >> 3, ch = cid & 7;
      const int sch = ch ^ (row & 7);
      load_lds16(A + (size_t)(m0 + row) * 512 + k0 + (sch << 3),
                 (uint4*)sm.k.A + (cid - lane));
      load_lds16(BT + (size_t)(n0 + row) * 512 + k0 + (sch << 3),
                 (uint4*)sm.k.B + (cid - lane));
    }
    __syncthreads();
#pragma unroll
    for (int kk = 0; kk < 2; ++kk) {
      const int q = (kk << 2) + kg;
      bf16x8 a[2], b[4];
#pragma unroll
      for (int mt = 0; mt < 2; ++mt) {
        const int rr = (wr << 5) + (mt << 4) + l16;
        a[mt] = __builtin_bit_cast(bf16x8, sm.k.A[rr][q ^ (rr & 7)]);
      }
#pragma unroll
      for (int nt = 0; nt < 4; ++nt) {
        const int rr = (wc << 6) + (nt << 4) + l16;
        b[nt] = __builtin_bit_cast(bf16x8, sm.k.B[rr][q ^ (rr & 7)]);
      }
#pragma unroll
      for (int mt = 0; mt < 2; ++mt)
#pragma unroll
        for (int nt = 0; nt < 4; ++nt)
          acc[mt][nt] = mfma16(a[mt], b[nt], acc[mt][nt]);
    }
    __syncthreads();
  }

  float bn[4];
#pragma unroll
  for (int nt = 0; nt < 4; ++nt)
    bn[nt] = bias[n0 + (wc << 6) + (nt << 4) + l16];

#pragma unroll
  for (int h = 0; h < 2; ++h) {
    __syncthreads();
    if ((wr >> 1) == h) {
#pragma unroll
      for (int mt = 0; mt < 2; ++mt) {
#pragma unroll
        for (int nt = 0; nt < 4; ++nt) {
          const int col = (wc << 6) + (nt << 4) + l16;
#pragma unroll
          for (int r = 0; r < 4; ++r) {
            const int rowl = ((wr & 1) << 5) + (mt << 4) + (kg << 2) + r;
            sm.ef[rowl][col] = fmaxf(acc[mt][nt][r] + bn[nt], 0.f);
          }
        }
      }
    }
    __syncthreads();
#pragma unroll
    for (int it = 0; it < 4; ++it) {
      const int c = tid + (it << 9);
      const int row = c >> 5, co = (c & 31) << 2;
      const f32x4 v = *(const f32x4*)&sm.ef[row][co];
      __builtin_nontemporal_store(
          v, (f32x4*)(out + (size_t)(m0 + (h << 6) + row) * 1024 + n0 + co));
    }
  }
}

}  // namespace

extern "C" void kernel_launch(void* const* d_in, const int* in_sizes, int n_in,
                              void* d_out, int out_size, void* d_ws, size_t ws_size,
                              hipStream_t stream) {
  (void)in_sizes; (void)n_in; (void)out_size; (void)ws_size;
  const float* x    = (const float*)d_in[0];
  const float* k_ud = (const float*)d_in[1];
  const float* r_ud = (const float*)d_in[2];
  const float* b_ud = (const float*)d_in[3];
  const float* k_du = (const float*)d_in[4];
  const float* r_du = (const float*)d_in[5];
  const float* b_du = (const float*)d_in[6];
  const float* k_lr = (const float*)d_in[7];
  const float* r_lr = (const float*)d_in[8];
  const float* b_lr = (const float*)d_in[9];
  const float* k_rl = (const float*)d_in[10];
  const float* r_rl = (const float*)d_in[11];
  const float* b_rl = (const float*)d_in[12];
  const float* Wd   = (const float*)d_in[13];
  const float* bd   = (const float*)d_in[14];

  ushort* W     = (ushort*)d_ws;
  ushort* Z     = W;                      // Zf: 2*128*65536 uint4 = 268 MB
  ushort* vbuf  = Z + 134217728;          // [64][32][32][512]    33554432
  ushort* rF    = vbuf + 33554432;        // [4][64][8][64][8]     1048576
  ushort* kTh   = rF + 1048576;           // [2][1024][512]        1048576
  ushort* WdT   = kTh + 1048576;          // [1024][512]            524288
  ushort* kfragV = WdT + 524288;          // [2][64][64][8]          65536
  uint4* Zf = (uint4*)Z;

  // ---- weight prep (merged launches) ----
  rfrag_all<<<dim3(128, 4), 256, 0, stream>>>(r_ud, r_du, r_lr, r_rl, rF);
  transpose_all<<<dim3(2048, 3), 256, 0, stream>>>(k_lr, k_rl, Wd, kTh,
                                                   kTh + 524288, WdT);
  kfragv_kernel<<<dim3(16, 2), 256, 0, stream>>>(k_ud, b_ud, k_du, b_du,
                                                 kfragV);

  // ---- vertical sweep (zx computed in-kernel; no Zf) ----
  lstm_sweepV<<<dim3(128, 2), 512, 0, stream>>>(x, kfragV, (const uint4*)rF,
                                                vbuf);

  // ---- horizontal input projection (both dirs, one launch, 8-wave) ----
  gemm_bt_dual<<<8192, 512, 0, stream>>>(vbuf, kTh, kTh + 524288, b_lr, b_rl,
                                         Zf);

  // ---- horizontal sweep (writes hfin over vbuf; reads only Zf) ----
  lstm_sweep7<<<dim3(128, 2), 512, 0, stream>>>(
      Zf, (const uint4*)(rF + 524288), vbuf, 0);

  // ---- dense + relu (8-wave) ----
  gemm_dense<<<4096, 512, 0, stream>>>(vbuf, WdT, bd, (float*)d_out);
}